// Round 10
// baseline (179.641 us; speedup 1.0000x reference)
//
#include <hip/hip_runtime.h>

#define B_    2
#define S_    1024
#define DM_   2048
#define H_    16
#define HD_   128
#define RD_   64
#define DQL_  384
#define DKVL_ 512
#define NTOK  (B_*S_)
#define CATD  (HD_+RD_)
#define LDSA  (128*64)
#define LDSB  (64*64)

typedef float f32x4 __attribute__((ext_vector_type(4)));
typedef short s16x8 __attribute__((ext_vector_type(8)));
typedef unsigned int u32;

__device__ __forceinline__ unsigned short f2b(float f) {   // fp32 -> bf16 RNE
  u32 u = __float_as_uint(f);
  u = (u + 0x7FFFu + ((u >> 16) & 1u)) >> 16;
  return (unsigned short)u;
}
__device__ __forceinline__ f32x4 mfma16(s16x8 a, s16x8 b, f32x4 c) {
  return __builtin_amdgcn_mfma_f32_16x16x32_bf16(a, b, c, 0, 0, 0);
}
__device__ __forceinline__ void gl_lds16(const void* g, void* l) {
  __builtin_amdgcn_global_load_lds((const __attribute__((address_space(1))) u32*)g,
                                   (__attribute__((address_space(3))) u32*)l, 16, 0, 0);
}

// ---- 512-thread 2-phase prefetch GEMM core: 128x64 tile, BK=64 dbuf, 48KB.
// 8 waves (4M x 2N), wave-tile 32x32, acc[2][2]. Same swizzle as round-7 core:
// pre-swizzled global source (linear gl_lds dest) + matching swizzled read.
__device__ __forceinline__ void gemm_core(const unsigned short* __restrict__ Ag,
                                          const unsigned short* __restrict__ Bg,
                                          int K,
                                          unsigned short (&As)[2][LDSA],
                                          unsigned short (&Bs)[2][LDSB],
                                          f32x4 (&acc)[2][2]) {
  const int tid = threadIdx.x;
  const int wave = tid >> 6, lane = tid & 63;
  const int wr = (wave >> 1) * 32, wc = (wave & 1) * 32;
  const int l16 = lane & 15, kg = lane >> 4;
  int sra[2], sca[2], srb, scb;
#pragma unroll
  for (int i = 0; i < 2; ++i) {
    const int g = i * 512 + tid;
    sra[i] = g >> 3;
    sca[i] = ((g & 7) ^ (sra[i] & 7)) * 8;
  }
  srb = tid >> 3;
  scb = ((tid & 7) ^ (srb & 7)) * 8;
  auto STAGE = [&](int b, int k0) {
#pragma unroll
    for (int i = 0; i < 2; ++i)
      gl_lds16(Ag + (size_t)sra[i] * K + k0 + sca[i], (void*)&As[b][(i * 512 + tid) * 8]);
    gl_lds16(Bg + (size_t)srb * K + k0 + scb, (void*)&Bs[b][tid * 8]);
  };
  STAGE(0, 0);
  int cur = 0;
  for (int k0 = 0; k0 < K; k0 += 64) {
    __syncthreads();
    if (k0 + 64 < K) STAGE(cur ^ 1, k0 + 64);
#pragma unroll
    for (int kk = 0; kk < 2; ++kk) {
      const int sl = ((kk * 4 + kg) ^ (l16 & 7)) * 8;
      s16x8 af[2], bf2[2];
#pragma unroll
      for (int i = 0; i < 2; ++i)
        af[i] = *reinterpret_cast<const s16x8*>(&As[cur][(wr + i * 16 + l16) * 64 + sl]);
#pragma unroll
      for (int i = 0; i < 2; ++i)
        bf2[i] = *reinterpret_cast<const s16x8*>(&Bs[cur][(wc + i * 16 + l16) * 64 + sl]);
#pragma unroll
      for (int mi = 0; mi < 2; ++mi)
#pragma unroll
        for (int ni = 0; ni < 2; ++ni)
          acc[mi][ni] = mfma16(af[mi], bf2[ni], acc[mi][ni]);
    }
    cur ^= 1;
  }
}

// ---------------- prep: rope table + weight transposes + x f2b, one launch ----
struct TD { const float* in; unsigned short* out; int R, C, blk0; float scale; };
struct TD8 { TD d[8]; };
__global__ __launch_bounds__(256) void k_prep(TD8 descs, float2* __restrict__ csT,
                                              const float* __restrict__ x,
                                              unsigned short* __restrict__ xb) {
  __shared__ float tile[64][65];
  const int bid = blockIdx.x;
  const int t = threadIdx.x;
  if (bid < 128) {
    const int i = bid * 256 + t;
    const int s = i >> 5, p = i & 31;
    const float freq = powf(10000.0f, -(float)p / 32.0f);
    float sn, cs;
    sincosf((float)s * freq, &sn, &cs);
    csT[i] = make_float2(cs, sn);
    return;
  }
  if (bid >= 3328) {
    const int i = (bid - 3328) * 256 + t;
    const float4 v = reinterpret_cast<const float4*>(x)[i];
    ushort4 o;
    o.x = f2b(v.x); o.y = f2b(v.y); o.z = f2b(v.z); o.w = f2b(v.w);
    reinterpret_cast<ushort4*>(xb)[i] = o;
    return;
  }
  int di = 0;
#pragma unroll
  for (int i = 1; i < 8; ++i) if (bid >= descs.d[i].blk0) di = i;
  const TD dd = descs.d[di];
  const int local = bid - dd.blk0;
  const int tiles_r = dd.R >> 6;
  const int tr_ = local % tiles_r, tc_ = local / tiles_r;
  const int r0 = tr_ * 64, c0 = tc_ * 64;
  const int tr = t >> 4, tc4 = (t & 15) * 4;
#pragma unroll
  for (int i = 0; i < 4; ++i) {
    const int rr = tr + i * 16;
    const float4 v = *reinterpret_cast<const float4*>(dd.in + (size_t)(r0 + rr) * dd.C + c0 + tc4);
    tile[rr][tc4 + 0] = v.x; tile[rr][tc4 + 1] = v.y;
    tile[rr][tc4 + 2] = v.z; tile[rr][tc4 + 3] = v.w;
  }
  __syncthreads();
#pragma unroll
  for (int i = 0; i < 4; ++i) {
    const int oc = tr + i * 16;
    ushort4 o;
    o.x = f2b(tile[tc4 + 0][oc] * dd.scale); o.y = f2b(tile[tc4 + 1][oc] * dd.scale);
    o.z = f2b(tile[tc4 + 2][oc] * dd.scale); o.w = f2b(tile[tc4 + 3][oc] * dd.scale);
    *reinterpret_cast<ushort4*>(dd.out + (size_t)(c0 + oc) * dd.R + r0 + tc4) = o;
  }
}

// ---------------- Wout GEMM: 512 blocks x 512 thr (128x64 tiles) ----------------
__global__ __launch_bounds__(512, 4) void k_gemm2(const unsigned short* __restrict__ A,
                                                  const unsigned short* __restrict__ Bt,
                                                  float* __restrict__ C,
                                                  int M, int N, int K) {
  __shared__ unsigned short As[2][LDSA];
  __shared__ unsigned short Bs[2][LDSB];
  const int mt = M >> 7;
  const int nwg = mt * (N >> 6);
  int id = blockIdx.x;
  id = (id & 7) * (nwg >> 3) + (id >> 3);
  const int tm = (id % mt) * 128;
  const int tn = (id / mt) * 64;
  const int tid = threadIdx.x;
  const int wave = tid >> 6, lane = tid & 63;
  const int wr = (wave >> 1) * 32, wc = (wave & 1) * 32;
  const int l16 = lane & 15, kg = lane >> 4;

  f32x4 acc[2][2] = {};
  gemm_core(A + (size_t)tm * K, Bt + (size_t)tn * K, K, As, Bs, acc);

#pragma unroll
  for (int mi = 0; mi < 2; ++mi)
#pragma unroll
    for (int ni = 0; ni < 2; ++ni) {
      const int rr = tm + wr + mi * 16 + kg * 4;
      const int cc = tn + wc + ni * 16 + l16;
#pragma unroll
      for (int j = 0; j < 4; ++j)
        C[(size_t)(rr + j) * N + cc] = acc[mi][ni][j];
    }
}

// ---------------- launch 1: A=xb. down(N=896)->cdown ; rope(N=2048)->Qcat/Kcat --
__global__ __launch_bounds__(512, 4) void k_proj_a(const unsigned short* __restrict__ xb,
                                                   const unsigned short* __restrict__ WdT,
                                                   const unsigned short* __restrict__ WrT,
                                                   float* __restrict__ cdown,
                                                   unsigned short* __restrict__ Qcat,
                                                   unsigned short* __restrict__ Kcat,
                                                   const float2* __restrict__ csT) {
  __shared__ unsigned short As[2][LDSA];
  __shared__ unsigned short Bs[2][LDSB];
  int id = blockIdx.x;
  id = (id & 7) * 92 + (id >> 3);
  const bool down = id < 224;
  int gm, tn; const unsigned short* Bt;
  if (down) { gm = id % 16; tn = (id / 16) * 64; Bt = WdT; }
  else { const int i2 = id - 224; gm = i2 % 16; tn = (i2 / 16) * 64; Bt = WrT; }
  const int tm = gm * 128;

  const int tid = threadIdx.x;
  const int wave = tid >> 6, lane = tid & 63;
  const int wr = (wave >> 1) * 32, wc = (wave & 1) * 32;
  const int l16 = lane & 15, kg = lane >> 4;

  f32x4 acc[2][2] = {};
  gemm_core(xb + (size_t)tm * DM_, Bt + (size_t)tn * DM_, DM_, As, Bs, acc);

  if (down) {
#pragma unroll
    for (int mi = 0; mi < 2; ++mi)
#pragma unroll
      for (int ni = 0; ni < 2; ++ni) {
        const int rr = tm + wr + mi * 16 + kg * 4;
        const int cc = tn + wc + ni * 16 + l16;
#pragma unroll
        for (int j = 0; j < 4; ++j)
          cdown[(size_t)(rr + j) * (DQL_ + DKVL_) + cc] = acc[mi][ni][j];
      }
  } else {
#pragma unroll
    for (int mi = 0; mi < 2; ++mi)
#pragma unroll
      for (int ni = 0; ni < 2; ++ni) {
        const int col = tn + wc + ni * 16 + l16;
        unsigned short* dst = (col < 1024) ? Qcat : Kcat;
        const int c1 = col & 1023;
        const int hh = c1 >> 6, dd2 = c1 & 63, p = dd2 >> 1, odd = dd2 & 1;
        const int row0 = tm + wr + mi * 16 + kg * 4;
#pragma unroll
        for (int j = 0; j < 4; ++j) {
          const float own = acc[mi][ni][j];
          const float prt = __shfl_xor(own, 1, 64);
          const int tok = row0 + j, b = tok >> 10, s = tok & 1023;
          const float2 cs = csT[s * 32 + p];
          const float o = odd ? (prt * cs.y + own * cs.x) : (own * cs.x - prt * cs.y);
          dst[((size_t)(b * H_ + hh) * S_ + s) * CATD + HD_ + dd2] = f2b(o);
        }
      }
  }
}

// ---------------- launch 2: q-up + kv-up -> Qcat/Kcat/VT. 1536 blocks ----------
__global__ __launch_bounds__(512, 4) void k_proj_b(const unsigned short* __restrict__ cqb,
                                                   const unsigned short* __restrict__ ckvb,
                                                   const unsigned short* __restrict__ WqupT,
                                                   const unsigned short* __restrict__ WkvupT,
                                                   unsigned short* __restrict__ Qcat,
                                                   unsigned short* __restrict__ Kcat,
                                                   unsigned short* __restrict__ VTb) {
  __shared__ unsigned short As[2][LDSA];
  __shared__ unsigned short Bs[2][LDSB];
  int id = blockIdx.x;
  id = (id & 7) * 192 + (id >> 3);
  const bool qgrp = id < 512;
  int gm, tn, K; const unsigned short* Bt; const unsigned short* A;
  if (qgrp) { gm = id & 15; tn = (id >> 4) * 64; Bt = WqupT; A = cqb; K = DQL_; }
  else { const int i2 = id - 512; gm = i2 & 15; tn = (i2 >> 4) * 64; Bt = WkvupT; A = ckvb; K = DKVL_; }
  const int tm = gm * 128;

  const int tid = threadIdx.x;
  const int wave = tid >> 6, lane = tid & 63;
  const int wr = (wave >> 1) * 32, wc = (wave & 1) * 32;
  const int l16 = lane & 15, kg = lane >> 4;

  f32x4 acc[2][2] = {};
  gemm_core(A + (size_t)tm * K, Bt + (size_t)tn * K, K, As, Bs, acc);

#pragma unroll
  for (int mi = 0; mi < 2; ++mi)
#pragma unroll
    for (int ni = 0; ni < 2; ++ni) {
      const int col = tn + wc + ni * 16 + l16;
      const int row0 = tm + wr + mi * 16 + kg * 4;
      if (qgrp || col < 2048) {
        unsigned short* dst = qgrp ? Qcat : Kcat;
        const int hh = (col & 2047) >> 7, d = col & 127;
#pragma unroll
        for (int j = 0; j < 4; ++j) {
          const int tok = row0 + j, b = tok >> 10, s = tok & 1023;
          dst[((size_t)(b * H_ + hh) * S_ + s) * CATD + d] = f2b(acc[mi][ni][j]);
        }
      } else {
        const int m2 = col - 2048;
        const int hh = m2 >> 7, d = m2 & 127;
        const int b = row0 >> 10, s0 = row0 & 1023;
        ushort4 o;
        o.x = f2b(acc[mi][ni][0]); o.y = f2b(acc[mi][ni][1]);
        o.z = f2b(acc[mi][ni][2]); o.w = f2b(acc[mi][ni][3]);
        *reinterpret_cast<ushort4*>(&VTb[((size_t)(b * H_ + hh) * HD_ + d) * S_ + s0]) = o;
      }
    }
}

// ---------------- RMSNorm, q+kv in one launch (4096 blocks) ----------------
__global__ __launch_bounds__(64) void k_rmsnorm2(const float* __restrict__ cdown,
                                                 const float* __restrict__ qw,
                                                 const float* __restrict__ kvw,
                                                 unsigned short* __restrict__ cqb,
                                                 unsigned short* __restrict__ ckvb) {
  const int row = blockIdx.x;
  const bool isq = row < NTOK;
  const int r = isq ? row : row - NTOK;
  const int D = isq ? DQL_ : DKVL_;
  const float* x = cdown + (size_t)r * (DQL_ + DKVL_) + (isq ? 0 : DQL_);
  const float* w = isq ? qw : kvw;
  unsigned short* out = (isq ? cqb : ckvb) + (size_t)r * D;
  float ss = 0.f;
  for (int i = threadIdx.x; i < D; i += 64) { const float v = x[i]; ss = fmaf(v, v, ss); }
#pragma unroll
  for (int off = 32; off; off >>= 1) ss += __shfl_xor(ss, off, 64);
  const float rr = rsqrtf(ss / (float)D + 1e-6f);
  for (int i = threadIdx.x; i < D; i += 64) out[i] = f2b(x[i] * rr * w[i]);
}

// ---------------- fused attention: 512 blocks x 256 thr, 2 blocks/CU ----------
#define KVB 64
__global__ __launch_bounds__(256, 2) void k_attn3(const unsigned short* __restrict__ Qcat,
                                                  const unsigned short* __restrict__ Kcat,
                                                  const unsigned short* __restrict__ VT,
                                                  float* __restrict__ attn_out,
                                                  unsigned short* __restrict__ ctx) {
  __shared__ unsigned short Ks[2][KVB * 192];   // 48 KB
  __shared__ unsigned short Vs[128 * 64];       // 16 KB
  __shared__ unsigned short Pl[4][16 * 64];     // 8 KB
  const int d0 = blockIdx.x;
  const int xcd = d0 & 7, i0 = d0 >> 3;
  const int bh = xcd + ((i0 >> 4) << 3);
  const int qc = i0 & 15;
  const int b = bh >> 4, h = bh & 15;

  const int tid = threadIdx.x, wave = tid >> 6, lane = tid & 63;
  const int l16 = lane & 15, kg = lane >> 4;
  const int qw = qc * 64 + wave * 16;

  const unsigned short* Qb = Qcat + ((size_t)bh * S_ + qw) * CATD;
  s16x8 qf[6];
#pragma unroll
  for (int ks = 0; ks < 6; ++ks)
    qf[ks] = *reinterpret_cast<const s16x8*>(Qb + (size_t)l16 * CATD + ks * 32 + kg * 8);

  int srk[6], sck[6];
#pragma unroll
  for (int j = 0; j < 6; ++j) {
    const int s = j * 256 + tid;
    srk[j] = s / 24;
    sck[j] = ((s % 24) ^ (srk[j] & 7)) * 8;
  }
  const unsigned short* Kb = Kcat + (size_t)bh * S_ * CATD;
  auto STAGE_K = [&](int bb, int ch) {
    const unsigned short* Kc = Kb + (size_t)ch * KVB * CATD;
#pragma unroll
    for (int j = 0; j < 6; ++j)
      gl_lds16(Kc + (size_t)srk[j] * CATD + sck[j], (void*)&Ks[bb][(j * 256 + tid) * 8]);
  };

  const unsigned short* Vb = VT + (size_t)bh * HD_ * S_;
  int srv[4], scv[4];
#pragma unroll
  for (int i = 0; i < 4; ++i) {
    const int g = i * 256 + tid;
    srv[i] = g >> 3;
    scv[i] = ((g & 7) ^ (srv[i] & 7)) * 8;
  }
  auto STAGE_V = [&](int ch) {
#pragma unroll
    for (int i = 0; i < 4; ++i)
      gl_lds16(Vb + (size_t)srv[i] * S_ + ch * KVB + scv[i], (void*)&Vs[(i * 256 + tid) * 8]);
  };

  f32x4 oacc[8] = {};
  float mx = -1e30f, sm = 0.f, rl = 0.f;

  STAGE_K(0, 0);
  int cur = 0;
  for (int g = 0; g < 32; ++g) {
    __syncthreads();                        // Ks[cur] ready; Vs/Pl consumed
    const int ch = g & 15;
    const bool p2 = g >= 16;
    if (p2) STAGE_V(ch);                    // 4 gl_lds; gated by counted vmcnt below
    if (g < 31) STAGE_K(cur ^ 1, (g + 1) & 15);   // 6 gl_lds stay in flight

    f32x4 acc[4] = {};
    __builtin_amdgcn_s_setprio(1);
#pragma unroll
    for (int ni = 0; ni < 4; ++ni) {
      const int row = ni * 16 + l16;
#pragma unroll
      for (int ks = 0; ks < 6; ++ks) {
        const int slot = (ks * 4 + kg) ^ (l16 & 7);
        const s16x8 af = *reinterpret_cast<const s16x8*>(&Ks[cur][row * 192 + slot * 8]);
        acc[ni] = mfma16(af, qf[ks], acc[ni]);
      }
    }
    __builtin_amdgcn_s_setprio(0);

    if (!p2) {
      float cm = -1e30f;
#pragma unroll
      for (int ni = 0; ni < 4; ++ni)
#pragma unroll
        for (int j = 0; j < 4; ++j) cm = fmaxf(cm, acc[ni][j]);
      const float nm = fmaxf(mx, cm);
      sm *= __expf(mx - nm);
#pragma unroll
      for (int ni = 0; ni < 4; ++ni)
#pragma unroll
        for (int j = 0; j < 4; ++j) sm += __expf(acc[ni][j] - nm);
      mx = nm;
      if (g == 15) {                        // combine the 4 kg-group k-subsets
#pragma unroll
        for (int off = 16; off < 64; off <<= 1) {
          const float om = __shfl_xor(mx, off, 64);
          const float os = __shfl_xor(sm, off, 64);
          const float nm2 = fmaxf(mx, om);
          sm = sm * __expf(mx - nm2) + os * __expf(om - nm2);
          mx = nm2;
        }
        rl = 1.0f / sm;
      }
    } else {
      // V-ready gate: outstanding = 4(V) + 6(K-prefetch); keep K in flight
      if (g < 31) asm volatile("s_waitcnt vmcnt(6)" ::: "memory");
      else        asm volatile("s_waitcnt vmcnt(0)" ::: "memory");
      __builtin_amdgcn_s_barrier();
      __builtin_amdgcn_sched_barrier(0);

      float* Ao = attn_out + ((size_t)bh * S_ + qw + l16) * S_ + ch * KVB;
      unsigned short* Pw = &Pl[wave][0];
#pragma unroll
      for (int ni = 0; ni < 4; ++ni) {
        float4 w4;
        w4.x = __expf(acc[ni][0] - mx) * rl;
        w4.y = __expf(acc[ni][1] - mx) * rl;
        w4.z = __expf(acc[ni][2] - mx) * rl;
        w4.w = __expf(acc[ni][3] - mx) * rl;
        *reinterpret_cast<float4*>(Ao + ni * 16 + kg * 4) = w4;
        ushort4 pb;
        pb.x = f2b(w4.x); pb.y = f2b(w4.y); pb.z = f2b(w4.z); pb.w = f2b(w4.w);
        *reinterpret_cast<ushort4*>(&Pw[l16 * 64 + (((ni * 4 + kg) ^ l16) * 4)]) = pb;
      }
      __builtin_amdgcn_s_setprio(1);
#pragma unroll
      for (int kk = 0; kk < 2; ++kk) {
        const short4 lo = *reinterpret_cast<const short4*>(&Pw[l16 * 64 + (((kk * 8 + kg * 2 + 0) ^ l16) * 4)]);
        const short4 hi = *reinterpret_cast<const short4*>(&Pw[l16 * 64 + (((kk * 8 + kg * 2 + 1) ^ l16) * 4)]);
        s16x8 pa;
        pa[0] = lo.x; pa[1] = lo.y; pa[2] = lo.z; pa[3] = lo.w;
        pa[4] = hi.x; pa[5] = hi.y; pa[6] = hi.z; pa[7] = hi.w;
#pragma unroll
        for (int ni = 0; ni < 8; ++ni) {
          const int row = ni * 16 + l16;
          const s16x8 vf = *reinterpret_cast<const s16x8*>(
              &Vs[row * 64 + (((kk * 4 + kg) ^ (l16 & 7)) * 8)]);
          oacc[ni] = mfma16(pa, vf, oacc[ni]);
        }
      }
      __builtin_amdgcn_s_setprio(0);
    }
    cur ^= 1;
  }

#pragma unroll
  for (int ni = 0; ni < 8; ++ni)
#pragma unroll
    for (int j = 0; j < 4; ++j)
      ctx[((size_t)(b * S_ + qw + kg * 4 + j)) * DM_ + h * HD_ + ni * 16 + l16] =
          f2b(oacc[ni][j]);
}

// ---------------- host launch ----------------
extern "C" void kernel_launch(void* const* d_in, const int* in_sizes, int n_in,
                              void* d_out, int out_size, void* d_ws, size_t ws_size,
                              hipStream_t stream) {
  const float* x         = (const float*)d_in[0];
  const float* Wq_down   = (const float*)d_in[1];
  const float* q_norm_w  = (const float*)d_in[2];
  const float* Wq_up     = (const float*)d_in[3];
  const float* Wq_rope   = (const float*)d_in[4];
  const float* Wkv_down  = (const float*)d_in[5];
  const float* kv_norm_w = (const float*)d_in[6];
  const float* Wk_up     = (const float*)d_in[7];
  const float* Wv_up     = (const float*)d_in[8];
  const float* Wk_rope   = (const float*)d_in[9];
  const float* Wout      = (const float*)d_in[10];

  float* out0 = (float*)d_out;
  float* attn = out0 + (size_t)B_ * S_ * DM_;

  char* ws = (char*)d_ws;
  size_t off = 0;
  auto alloc = [&](size_t bytes) -> void* {
    void* p = ws + off;
    off += (bytes + 255) & ~(size_t)255;
    return p;
  };

  unsigned short* xb     = (unsigned short*)alloc((size_t)NTOK * DM_ * 2);
  unsigned short* WdT    = (unsigned short*)alloc((size_t)(DQL_ + DKVL_) * DM_ * 2);
  unsigned short* WrT    = (unsigned short*)alloc((size_t)DM_ * DM_ * 2);
  unsigned short* WqupT  = (unsigned short*)alloc((size_t)DM_ * DQL_ * 2);
  unsigned short* WkvupT = (unsigned short*)alloc((size_t)(2 * DM_) * DKVL_ * 2);
  unsigned short* WoutT  = (unsigned short*)alloc((size_t)DM_ * DM_ * 2);
  float* cdown           = (float*)alloc((size_t)NTOK * (DQL_ + DKVL_) * 4);
  unsigned short* cqb    = (unsigned short*)alloc((size_t)NTOK * DQL_ * 2);
  unsigned short* ckvb   = (unsigned short*)alloc((size_t)NTOK * DKVL_ * 2);
  unsigned short* Qcat   = (unsigned short*)alloc((size_t)B_ * H_ * S_ * CATD * 2);
  unsigned short* Kcat   = (unsigned short*)alloc((size_t)B_ * H_ * S_ * CATD * 2);
  unsigned short* VTb    = (unsigned short*)alloc((size_t)B_ * H_ * HD_ * S_ * 2);
  unsigned short* ctxb   = (unsigned short*)alloc((size_t)NTOK * DM_ * 2);
  float2* csT            = (float2*)alloc((size_t)S_ * 32 * sizeof(float2));

  if (off > ws_size) return;

  const float qsc = 0.07216878364870323f;    // 192^-0.5 folded into Wq_up / Wq_rope

  TD8 td;
  int blk0 = 128;
  auto setd = [&](int i, const float* in, unsigned short* out, int R, int C, float sc) {
    td.d[i] = TD{in, out, R, C, blk0, sc};
    blk0 += (R >> 6) * (C >> 6);
  };
  setd(0, Wq_down,  WdT,                        DM_,  DQL_,  1.0f);
  setd(1, Wkv_down, WdT + (size_t)DQL_ * DM_,   DM_,  DKVL_, 1.0f);
  setd(2, Wq_rope,  WrT,                        DM_,  1024,  qsc);
  setd(3, Wk_rope,  WrT + (size_t)1024 * DM_,   DM_,  1024,  1.0f);
  setd(4, Wq_up,    WqupT,                      DQL_, DM_,   qsc);
  setd(5, Wk_up,    WkvupT,                     DKVL_, DM_,  1.0f);
  setd(6, Wv_up,    WkvupT + (size_t)DM_ * DKVL_, DKVL_, DM_, 1.0f);
  setd(7, Wout,     WoutT,                      DM_,  DM_,   1.0f);
  k_prep<<<3328 + (NTOK * DM_ / 4) / 256, 256, 0, stream>>>(td, csT, x, xb);

  k_proj_a<<<736, 512, 0, stream>>>(xb, WdT, WrT, cdown, Qcat, Kcat, csT);
  k_rmsnorm2<<<2 * NTOK, 64, 0, stream>>>(cdown, q_norm_w, kv_norm_w, cqb, ckvb);
  k_proj_b<<<1536, 512, 0, stream>>>(cqb, ckvb, WqupT, WkvupT, Qcat, Kcat, VTb);

  k_attn3<<<512, 256, 0, stream>>>(Qcat, Kcat, VTb, attn, ctxb);

  k_gemm2<<<512, 512, 0, stream>>>(ctxb, WoutT, out0, NTOK, DM_, DM_);
}

// Round 11
// 176.366 us; speedup vs baseline: 1.0186x; 1.0186x over previous
//
#include <hip/hip_runtime.h>

#define B_    2
#define S_    1024
#define DM_   2048
#define H_    16
#define HD_   128
#define RD_   64
#define DQL_  384
#define DKVL_ 512
#define NTOK  (B_*S_)
#define CATD  (HD_+RD_)
#define LDSA  (128*64)
#define LDSB  (64*64)

typedef float f32x4 __attribute__((ext_vector_type(4)));
typedef short s16x8 __attribute__((ext_vector_type(8)));
typedef unsigned int u32;

__device__ __forceinline__ unsigned short f2b(float f) {   // fp32 -> bf16 RNE
  u32 u = __float_as_uint(f);
  u = (u + 0x7FFFu + ((u >> 16) & 1u)) >> 16;
  return (unsigned short)u;
}
__device__ __forceinline__ f32x4 mfma16(s16x8 a, s16x8 b, f32x4 c) {
  return __builtin_amdgcn_mfma_f32_16x16x32_bf16(a, b, c, 0, 0, 0);
}
__device__ __forceinline__ void gl_lds16(const void* g, void* l) {
  __builtin_amdgcn_global_load_lds((const __attribute__((address_space(1))) u32*)g,
                                   (__attribute__((address_space(3))) u32*)l, 16, 0, 0);
}

// ---- 256-thread 2-phase prefetch GEMM core (round-7/9 proven): BK=64 dbuf, 48KB.
// XOR-swizzle via pre-swizzled global source (linear dest) + swizzled read.
__device__ __forceinline__ void gemm_core(const unsigned short* __restrict__ Ag,
                                          const unsigned short* __restrict__ Bg,
                                          int K,
                                          unsigned short (&As)[2][LDSA],
                                          unsigned short (&Bs)[2][LDSB],
                                          f32x4 (&acc)[4][2]) {
  const int tid = threadIdx.x;
  const int wave = tid >> 6, lane = tid & 63;
  const int wr = (wave >> 1) * 64, wc = (wave & 1) * 32;
  const int l16 = lane & 15, kg = lane >> 4;
  int sra[4], sca[4], srb[2], scb[2];
#pragma unroll
  for (int i = 0; i < 4; ++i) {
    const int g = i * 256 + tid;
    sra[i] = g >> 3;
    sca[i] = ((g & 7) ^ (sra[i] & 7)) * 8;
  }
#pragma unroll
  for (int i = 0; i < 2; ++i) {
    const int g = i * 256 + tid;
    srb[i] = g >> 3;
    scb[i] = ((g & 7) ^ (srb[i] & 7)) * 8;
  }
  auto STAGE = [&](int b, int k0) {
#pragma unroll
    for (int i = 0; i < 4; ++i)
      gl_lds16(Ag + (size_t)sra[i] * K + k0 + sca[i], (void*)&As[b][(i * 256 + tid) * 8]);
#pragma unroll
    for (int i = 0; i < 2; ++i)
      gl_lds16(Bg + (size_t)srb[i] * K + k0 + scb[i], (void*)&Bs[b][(i * 256 + tid) * 8]);
  };
  STAGE(0, 0);
  int cur = 0;
  for (int k0 = 0; k0 < K; k0 += 64) {
    __syncthreads();
    if (k0 + 64 < K) STAGE(cur ^ 1, k0 + 64);
#pragma unroll
    for (int kk = 0; kk < 2; ++kk) {
      const int sl = ((kk * 4 + kg) ^ (l16 & 7)) * 8;
      s16x8 af[4], bf2[2];
#pragma unroll
      for (int i = 0; i < 4; ++i)
        af[i] = *reinterpret_cast<const s16x8*>(&As[cur][(wr + i * 16 + l16) * 64 + sl]);
#pragma unroll
      for (int i = 0; i < 2; ++i)
        bf2[i] = *reinterpret_cast<const s16x8*>(&Bs[cur][(wc + i * 16 + l16) * 64 + sl]);
#pragma unroll
      for (int mi = 0; mi < 4; ++mi)
#pragma unroll
        for (int ni = 0; ni < 2; ++ni)
          acc[mi][ni] = mfma16(af[mi], bf2[ni], acc[mi][ni]);
    }
    cur ^= 1;
  }
}

// ---------------- prep: rope table + weight transposes + x f2b, one launch ----
struct TD { const float* in; unsigned short* out; int R, C, blk0; float scale; };
struct TD8 { TD d[8]; };
__global__ __launch_bounds__(256) void k_prep(TD8 descs, float2* __restrict__ csT,
                                              const float* __restrict__ x,
                                              unsigned short* __restrict__ xb) {
  __shared__ float tile[64][65];
  const int bid = blockIdx.x;
  const int t = threadIdx.x;
  if (bid < 128) {
    const int i = bid * 256 + t;
    const int s = i >> 5, p = i & 31;
    const float freq = powf(10000.0f, -(float)p / 32.0f);
    float sn, cs;
    sincosf((float)s * freq, &sn, &cs);
    csT[i] = make_float2(cs, sn);
    return;
  }
  if (bid >= 3328) {
    const int i = (bid - 3328) * 256 + t;
    const float4 v = reinterpret_cast<const float4*>(x)[i];
    ushort4 o;
    o.x = f2b(v.x); o.y = f2b(v.y); o.z = f2b(v.z); o.w = f2b(v.w);
    reinterpret_cast<ushort4*>(xb)[i] = o;
    return;
  }
  int di = 0;
#pragma unroll
  for (int i = 1; i < 8; ++i) if (bid >= descs.d[i].blk0) di = i;
  const TD dd = descs.d[di];
  const int local = bid - dd.blk0;
  const int tiles_r = dd.R >> 6;
  const int tr_ = local % tiles_r, tc_ = local / tiles_r;
  const int r0 = tr_ * 64, c0 = tc_ * 64;
  const int tr = t >> 4, tc4 = (t & 15) * 4;
#pragma unroll
  for (int i = 0; i < 4; ++i) {
    const int rr = tr + i * 16;
    const float4 v = *reinterpret_cast<const float4*>(dd.in + (size_t)(r0 + rr) * dd.C + c0 + tc4);
    tile[rr][tc4 + 0] = v.x; tile[rr][tc4 + 1] = v.y;
    tile[rr][tc4 + 2] = v.z; tile[rr][tc4 + 3] = v.w;
  }
  __syncthreads();
#pragma unroll
  for (int i = 0; i < 4; ++i) {
    const int oc = tr + i * 16;
    ushort4 o;
    o.x = f2b(tile[tc4 + 0][oc] * dd.scale); o.y = f2b(tile[tc4 + 1][oc] * dd.scale);
    o.z = f2b(tile[tc4 + 2][oc] * dd.scale); o.w = f2b(tile[tc4 + 3][oc] * dd.scale);
    *reinterpret_cast<ushort4*>(dd.out + (size_t)(c0 + oc) * dd.R + r0 + tc4) = o;
  }
}

// ---------------- Wout GEMM: 512 blocks (128x64 tiles) ----------------
__global__ __launch_bounds__(256, 4) void k_gemm2(const unsigned short* __restrict__ A,
                                                  const unsigned short* __restrict__ Bt,
                                                  float* __restrict__ C,
                                                  int M, int N, int K) {
  __shared__ unsigned short As[2][LDSA];
  __shared__ unsigned short Bs[2][LDSB];
  const int mt = M >> 7;
  const int nwg = mt * (N >> 6);
  int id = blockIdx.x;
  id = (id & 7) * (nwg >> 3) + (id >> 3);
  const int tm = (id % mt) * 128;
  const int tn = (id / mt) * 64;
  const int tid = threadIdx.x;
  const int wave = tid >> 6, lane = tid & 63;
  const int wr = (wave >> 1) * 64, wc = (wave & 1) * 32;
  const int l16 = lane & 15, kg = lane >> 4;

  f32x4 acc[4][2] = {};
  gemm_core(A + (size_t)tm * K, Bt + (size_t)tn * K, K, As, Bs, acc);

#pragma unroll
  for (int mi = 0; mi < 4; ++mi)
#pragma unroll
    for (int ni = 0; ni < 2; ++ni) {
      const int rr = tm + wr + mi * 16 + kg * 4;
      const int cc = tn + wc + ni * 16 + l16;
#pragma unroll
      for (int j = 0; j < 4; ++j)
        C[(size_t)(rr + j) * N + cc] = acc[mi][ni][j];
    }
}

// ---------------- launch 1: A=xb. down(N=896)->cdown ; rope(N=2048)->Qcat/Kcat --
__global__ __launch_bounds__(256, 4) void k_proj_a(const unsigned short* __restrict__ xb,
                                                   const unsigned short* __restrict__ WdT,
                                                   const unsigned short* __restrict__ WrT,
                                                   float* __restrict__ cdown,
                                                   unsigned short* __restrict__ Qcat,
                                                   unsigned short* __restrict__ Kcat,
                                                   const float2* __restrict__ csT) {
  __shared__ unsigned short As[2][LDSA];
  __shared__ unsigned short Bs[2][LDSB];
  int id = blockIdx.x;
  id = (id & 7) * 92 + (id >> 3);
  const bool down = id < 224;
  int gm, tn; const unsigned short* Bt;
  if (down) { gm = id % 16; tn = (id / 16) * 64; Bt = WdT; }
  else { const int i2 = id - 224; gm = i2 % 16; tn = (i2 / 16) * 64; Bt = WrT; }
  const int tm = gm * 128;

  const int tid = threadIdx.x;
  const int wave = tid >> 6, lane = tid & 63;
  const int wr = (wave >> 1) * 64, wc = (wave & 1) * 32;
  const int l16 = lane & 15, kg = lane >> 4;

  f32x4 acc[4][2] = {};
  gemm_core(xb + (size_t)tm * DM_, Bt + (size_t)tn * DM_, DM_, As, Bs, acc);

  if (down) {
#pragma unroll
    for (int mi = 0; mi < 4; ++mi)
#pragma unroll
      for (int ni = 0; ni < 2; ++ni) {
        const int rr = tm + wr + mi * 16 + kg * 4;
        const int cc = tn + wc + ni * 16 + l16;
#pragma unroll
        for (int j = 0; j < 4; ++j)
          cdown[(size_t)(rr + j) * (DQL_ + DKVL_) + cc] = acc[mi][ni][j];
      }
  } else {
#pragma unroll
    for (int mi = 0; mi < 4; ++mi)
#pragma unroll
      for (int ni = 0; ni < 2; ++ni) {
        const int col = tn + wc + ni * 16 + l16;
        unsigned short* dst = (col < 1024) ? Qcat : Kcat;
        const int c1 = col & 1023;
        const int hh = c1 >> 6, dd2 = c1 & 63, p = dd2 >> 1, odd = dd2 & 1;
        const int row0 = tm + wr + mi * 16 + kg * 4;
#pragma unroll
        for (int j = 0; j < 4; ++j) {
          const float own = acc[mi][ni][j];
          const float prt = __shfl_xor(own, 1, 64);
          const int tok = row0 + j, b = tok >> 10, s = tok & 1023;
          const float2 cs = csT[s * 32 + p];
          const float o = odd ? (prt * cs.y + own * cs.x) : (own * cs.x - prt * cs.y);
          dst[((size_t)(b * H_ + hh) * S_ + s) * CATD + HD_ + dd2] = f2b(o);
        }
      }
  }
}

// ---------------- launch 2: q-up + kv-up -> Qcat/Kcat/VT. 1536 blocks ----------
__global__ __launch_bounds__(256, 4) void k_proj_b(const unsigned short* __restrict__ cqb,
                                                   const unsigned short* __restrict__ ckvb,
                                                   const unsigned short* __restrict__ WqupT,
                                                   const unsigned short* __restrict__ WkvupT,
                                                   unsigned short* __restrict__ Qcat,
                                                   unsigned short* __restrict__ Kcat,
                                                   unsigned short* __restrict__ VTb) {
  __shared__ unsigned short As[2][LDSA];
  __shared__ unsigned short Bs[2][LDSB];
  int id = blockIdx.x;
  id = (id & 7) * 192 + (id >> 3);
  const bool qgrp = id < 512;
  int gm, tn, K; const unsigned short* Bt; const unsigned short* A;
  if (qgrp) { gm = id & 15; tn = (id >> 4) * 64; Bt = WqupT; A = cqb; K = DQL_; }
  else { const int i2 = id - 512; gm = i2 & 15; tn = (i2 >> 4) * 64; Bt = WkvupT; A = ckvb; K = DKVL_; }
  const int tm = gm * 128;

  const int tid = threadIdx.x;
  const int wave = tid >> 6, lane = tid & 63;
  const int wr = (wave >> 1) * 64, wc = (wave & 1) * 32;
  const int l16 = lane & 15, kg = lane >> 4;

  f32x4 acc[4][2] = {};
  gemm_core(A + (size_t)tm * K, Bt + (size_t)tn * K, K, As, Bs, acc);

#pragma unroll
  for (int mi = 0; mi < 4; ++mi)
#pragma unroll
    for (int ni = 0; ni < 2; ++ni) {
      const int col = tn + wc + ni * 16 + l16;
      const int row0 = tm + wr + mi * 16 + kg * 4;
      if (qgrp || col < 2048) {
        unsigned short* dst = qgrp ? Qcat : Kcat;
        const int hh = (col & 2047) >> 7, d = col & 127;
#pragma unroll
        for (int j = 0; j < 4; ++j) {
          const int tok = row0 + j, b = tok >> 10, s = tok & 1023;
          dst[((size_t)(b * H_ + hh) * S_ + s) * CATD + d] = f2b(acc[mi][ni][j]);
        }
      } else {
        const int m2 = col - 2048;
        const int hh = m2 >> 7, d = m2 & 127;
        const int b = row0 >> 10, s0 = row0 & 1023;
        ushort4 o;
        o.x = f2b(acc[mi][ni][0]); o.y = f2b(acc[mi][ni][1]);
        o.z = f2b(acc[mi][ni][2]); o.w = f2b(acc[mi][ni][3]);
        *reinterpret_cast<ushort4*>(&VTb[((size_t)(b * H_ + hh) * HD_ + d) * S_ + s0]) = o;
      }
    }
}

// ---------------- RMSNorm, q+kv in one launch (4096 blocks) ----------------
__global__ __launch_bounds__(64) void k_rmsnorm2(const float* __restrict__ cdown,
                                                 const float* __restrict__ qw,
                                                 const float* __restrict__ kvw,
                                                 unsigned short* __restrict__ cqb,
                                                 unsigned short* __restrict__ ckvb) {
  const int row = blockIdx.x;
  const bool isq = row < NTOK;
  const int r = isq ? row : row - NTOK;
  const int D = isq ? DQL_ : DKVL_;
  const float* x = cdown + (size_t)r * (DQL_ + DKVL_) + (isq ? 0 : DQL_);
  const float* w = isq ? qw : kvw;
  unsigned short* out = (isq ? cqb : ckvb) + (size_t)r * D;
  float ss = 0.f;
  for (int i = threadIdx.x; i < D; i += 64) { const float v = x[i]; ss = fmaf(v, v, ss); }
#pragma unroll
  for (int off = 32; off; off >>= 1) ss += __shfl_xor(ss, off, 64);
  const float rr = rsqrtf(ss / (float)D + 1e-6f);
  for (int i = threadIdx.x; i < D; i += 64) out[i] = f2b(x[i] * rr * w[i]);
}

// ---------------- fused attention: 512 blocks x 256 thr, 2 blocks/CU ----------
#define KVB 64
__global__ __launch_bounds__(256, 2) void k_attn3(const unsigned short* __restrict__ Qcat,
                                                  const unsigned short* __restrict__ Kcat,
                                                  const unsigned short* __restrict__ VT,
                                                  float* __restrict__ attn_out,
                                                  unsigned short* __restrict__ ctx) {
  __shared__ unsigned short Ks[2][KVB * 192];   // 48 KB
  __shared__ unsigned short Vs[128 * 64];       // 16 KB
  __shared__ unsigned short Pl[4][16 * 64];     // 8 KB
  const int d0 = blockIdx.x;
  const int xcd = d0 & 7, i0 = d0 >> 3;
  const int bh = xcd + ((i0 >> 4) << 3);
  const int qc = i0 & 15;
  const int b = bh >> 4, h = bh & 15;

  const int tid = threadIdx.x, wave = tid >> 6, lane = tid & 63;
  const int l16 = lane & 15, kg = lane >> 4;
  const int qw = qc * 64 + wave * 16;

  const unsigned short* Qb = Qcat + ((size_t)bh * S_ + qw) * CATD;
  s16x8 qf[6];
#pragma unroll
  for (int ks = 0; ks < 6; ++ks)
    qf[ks] = *reinterpret_cast<const s16x8*>(Qb + (size_t)l16 * CATD + ks * 32 + kg * 8);

  int srk[6], sck[6];
#pragma unroll
  for (int j = 0; j < 6; ++j) {
    const int s = j * 256 + tid;
    srk[j] = s / 24;
    sck[j] = ((s % 24) ^ (srk[j] & 7)) * 8;
  }
  const unsigned short* Kb = Kcat + (size_t)bh * S_ * CATD;
  auto STAGE_K = [&](int bb, int ch) {
    const unsigned short* Kc = Kb + (size_t)ch * KVB * CATD;
#pragma unroll
    for (int j = 0; j < 6; ++j)
      gl_lds16(Kc + (size_t)srk[j] * CATD + sck[j], (void*)&Ks[bb][(j * 256 + tid) * 8]);
  };

  const unsigned short* Vb = VT + (size_t)bh * HD_ * S_;
  int srv[4], scv[4];
#pragma unroll
  for (int i = 0; i < 4; ++i) {
    const int g = i * 256 + tid;
    srv[i] = g >> 3;
    scv[i] = ((g & 7) ^ (srv[i] & 7)) * 8;
  }
  auto STAGE_V = [&](int ch) {
#pragma unroll
    for (int i = 0; i < 4; ++i)
      gl_lds16(Vb + (size_t)srv[i] * S_ + ch * KVB + scv[i], (void*)&Vs[(i * 256 + tid) * 8]);
  };

  f32x4 oacc[8] = {};
  float mx = -1e30f, sm = 0.f, rl = 0.f;

  STAGE_K(0, 0);
  int cur = 0;
  for (int g = 0; g < 32; ++g) {
    __syncthreads();                        // Ks[cur] ready; Vs/Pl consumed
    const int ch = g & 15;
    const bool p2 = g >= 16;
    if (p2) STAGE_V(ch);                    // 4 gl_lds; gated by counted vmcnt below
    if (g < 31) STAGE_K(cur ^ 1, (g + 1) & 15);   // 6 gl_lds stay in flight

    f32x4 acc[4] = {};
    __builtin_amdgcn_s_setprio(1);
#pragma unroll
    for (int ni = 0; ni < 4; ++ni) {
      const int row = ni * 16 + l16;
#pragma unroll
      for (int ks = 0; ks < 6; ++ks) {
        const int slot = (ks * 4 + kg) ^ (l16 & 7);
        const s16x8 af = *reinterpret_cast<const s16x8*>(&Ks[cur][row * 192 + slot * 8]);
        acc[ni] = mfma16(af, qf[ks], acc[ni]);
      }
    }
    __builtin_amdgcn_s_setprio(0);

    if (!p2) {
      float cm = -1e30f;
#pragma unroll
      for (int ni = 0; ni < 4; ++ni)
#pragma unroll
        for (int j = 0; j < 4; ++j) cm = fmaxf(cm, acc[ni][j]);
      const float nm = fmaxf(mx, cm);
      sm *= __expf(mx - nm);
#pragma unroll
      for (int ni = 0; ni < 4; ++ni)
#pragma unroll
        for (int j = 0; j < 4; ++j) sm += __expf(acc[ni][j] - nm);
      mx = nm;
      if (g == 15) {                        // combine the 4 kg-group k-subsets
#pragma unroll
        for (int off = 16; off < 64; off <<= 1) {
          const float om = __shfl_xor(mx, off, 64);
          const float os = __shfl_xor(sm, off, 64);
          const float nm2 = fmaxf(mx, om);
          sm = sm * __expf(mx - nm2) + os * __expf(om - nm2);
          mx = nm2;
        }
        rl = 1.0f / sm;
      }
    } else {
      // V-ready gate: outstanding = 4(V) + 6(K-prefetch); keep K in flight
      if (g < 31) asm volatile("s_waitcnt vmcnt(6)" ::: "memory");
      else        asm volatile("s_waitcnt vmcnt(0)" ::: "memory");
      __builtin_amdgcn_s_barrier();
      __builtin_amdgcn_sched_barrier(0);

      float* Ao = attn_out + ((size_t)bh * S_ + qw + l16) * S_ + ch * KVB;
      unsigned short* Pw = &Pl[wave][0];
#pragma unroll
      for (int ni = 0; ni < 4; ++ni) {
        float4 w4;
        w4.x = __expf(acc[ni][0] - mx) * rl;
        w4.y = __expf(acc[ni][1] - mx) * rl;
        w4.z = __expf(acc[ni][2] - mx) * rl;
        w4.w = __expf(acc[ni][3] - mx) * rl;
        *reinterpret_cast<float4*>(Ao + ni * 16 + kg * 4) = w4;
        ushort4 pb;
        pb.x = f2b(w4.x); pb.y = f2b(w4.y); pb.z = f2b(w4.z); pb.w = f2b(w4.w);
        *reinterpret_cast<ushort4*>(&Pw[l16 * 64 + (((ni * 4 + kg) ^ l16) * 4)]) = pb;
      }
      __builtin_amdgcn_s_setprio(1);
#pragma unroll
      for (int kk = 0; kk < 2; ++kk) {
        const short4 lo = *reinterpret_cast<const short4*>(&Pw[l16 * 64 + (((kk * 8 + kg * 2 + 0) ^ l16) * 4)]);
        const short4 hi = *reinterpret_cast<const short4*>(&Pw[l16 * 64 + (((kk * 8 + kg * 2 + 1) ^ l16) * 4)]);
        s16x8 pa;
        pa[0] = lo.x; pa[1] = lo.y; pa[2] = lo.z; pa[3] = lo.w;
        pa[4] = hi.x; pa[5] = hi.y; pa[6] = hi.z; pa[7] = hi.w;
#pragma unroll
        for (int ni = 0; ni < 8; ++ni) {
          const int row = ni * 16 + l16;
          const s16x8 vf = *reinterpret_cast<const s16x8*>(
              &Vs[row * 64 + (((kk * 4 + kg) ^ (l16 & 7)) * 8)]);
          oacc[ni] = mfma16(pa, vf, oacc[ni]);
        }
      }
      __builtin_amdgcn_s_setprio(0);
    }
    cur ^= 1;
  }

#pragma unroll
  for (int ni = 0; ni < 8; ++ni)
#pragma unroll
    for (int j = 0; j < 4; ++j)
      ctx[((size_t)(b * S_ + qw + kg * 4 + j)) * DM_ + h * HD_ + ni * 16 + l16] =
          f2b(oacc[ni][j]);
}

// ---------------- host launch ----------------
extern "C" void kernel_launch(void* const* d_in, const int* in_sizes, int n_in,
                              void* d_out, int out_size, void* d_ws, size_t ws_size,
                              hipStream_t stream) {
  const float* x         = (const float*)d_in[0];
  const float* Wq_down   = (const float*)d_in[1];
  const float* q_norm_w  = (const float*)d_in[2];
  const float* Wq_up     = (const float*)d_in[3];
  const float* Wq_rope   = (const float*)d_in[4];
  const float* Wkv_down  = (const float*)d_in[5];
  const float* kv_norm_w = (const float*)d_in[6];
  const float* Wk_up     = (const float*)d_in[7];
  const float* Wv_up     = (const float*)d_in[8];
  const float* Wk_rope   = (const float*)d_in[9];
  const float* Wout      = (const float*)d_in[10];

  float* out0 = (float*)d_out;
  float* attn = out0 + (size_t)B_ * S_ * DM_;

  char* ws = (char*)d_ws;
  size_t off = 0;
  auto alloc = [&](size_t bytes) -> void* {
    void* p = ws + off;
    off += (bytes + 255) & ~(size_t)255;
    return p;
  };

  unsigned short* xb     = (unsigned short*)alloc((size_t)NTOK * DM_ * 2);
  unsigned short* WdT    = (unsigned short*)alloc((size_t)(DQL_ + DKVL_) * DM_ * 2);
  unsigned short* WrT    = (unsigned short*)alloc((size_t)DM_ * DM_ * 2);
  unsigned short* WqupT  = (unsigned short*)alloc((size_t)DM_ * DQL_ * 2);
  unsigned short* WkvupT = (unsigned short*)alloc((size_t)(2 * DM_) * DKVL_ * 2);
  unsigned short* WoutT  = (unsigned short*)alloc((size_t)DM_ * DM_ * 2);
  float* cdown           = (float*)alloc((size_t)NTOK * (DQL_ + DKVL_) * 4);
  unsigned short* cqb    = (unsigned short*)alloc((size_t)NTOK * DQL_ * 2);
  unsigned short* ckvb   = (unsigned short*)alloc((size_t)NTOK * DKVL_ * 2);
  unsigned short* Qcat   = (unsigned short*)alloc((size_t)B_ * H_ * S_ * CATD * 2);
  unsigned short* Kcat   = (unsigned short*)alloc((size_t)B_ * H_ * S_ * CATD * 2);
  unsigned short* VTb    = (unsigned short*)alloc((size_t)B_ * H_ * HD_ * S_ * 2);
  unsigned short* ctxb   = (unsigned short*)alloc((size_t)NTOK * DM_ * 2);
  float2* csT            = (float2*)alloc((size_t)S_ * 32 * sizeof(float2));

  if (off > ws_size) return;

  const float qsc = 0.07216878364870323f;    // 192^-0.5 folded into Wq_up / Wq_rope

  TD8 td;
  int blk0 = 128;
  auto setd = [&](int i, const float* in, unsigned short* out, int R, int C, float sc) {
    td.d[i] = TD{in, out, R, C, blk0, sc};
    blk0 += (R >> 6) * (C >> 6);
  };
  setd(0, Wq_down,  WdT,                        DM_,  DQL_,  1.0f);
  setd(1, Wkv_down, WdT + (size_t)DQL_ * DM_,   DM_,  DKVL_, 1.0f);
  setd(2, Wq_rope,  WrT,                        DM_,  1024,  qsc);
  setd(3, Wk_rope,  WrT + (size_t)1024 * DM_,   DM_,  1024,  1.0f);
  setd(4, Wq_up,    WqupT,                      DQL_, DM_,   qsc);
  setd(5, Wk_up,    WkvupT,                     DKVL_, DM_,  1.0f);
  setd(6, Wv_up,    WkvupT + (size_t)DM_ * DKVL_, DKVL_, DM_, 1.0f);
  setd(7, Wout,     WoutT,                      DM_,  DM_,   1.0f);
  k_prep<<<3328 + (NTOK * DM_ / 4) / 256, 256, 0, stream>>>(td, csT, x, xb);

  k_proj_a<<<736, 256, 0, stream>>>(xb, WdT, WrT, cdown, Qcat, Kcat, csT);
  k_rmsnorm2<<<2 * NTOK, 64, 0, stream>>>(cdown, q_norm_w, kv_norm_w, cqb, ckvb);
  k_proj_b<<<1536, 256, 0, stream>>>(cqb, ckvb, WqupT, WkvupT, Qcat, Kcat, VTb);

  k_attn3<<<512, 256, 0, stream>>>(Qcat, Kcat, VTb, attn, ctxb);

  k_gemm2<<<512, 256, 0, stream>>>(ctxb, WoutT, out0, NTOK, DM_, DM_);
}